// Round 2
// baseline (282.204 us; speedup 1.0000x reference)
//
#include <hip/hip_runtime.h>
#include <hip/hip_bf16.h>

// DCTBlur reference:  out = D (M .* (D x D^T)) D^T  with M = m m^T, m_k = exp(-(pi k/N)^2 t),
// t = sigma^2/2, sigma = blur_sigmas[fwd_steps[b]].
// => out = H x H^T  with  H = D diag(m) D   (NOT symmetric; per-step, 32 variants).
// Precompute H numerically (fp32) -> bf16; main kernel: Z = x H^T (phase 1, LDS),
// out = H Z (phase 2), both via mfma_f32_16x16x32_bf16.

#define NN 256
#define NSTEP 32

typedef __attribute__((ext_vector_type(8))) __bf16 bf16x8;
typedef __attribute__((ext_vector_type(4))) float f32x4;
typedef __attribute__((ext_vector_type(8))) unsigned short u16x8;
typedef __attribute__((ext_vector_type(4))) unsigned short u16x4;

__device__ __align__(16) float g_D[NN][NN];
__device__ __align__(16) unsigned short g_H[NSTEP][NN][NN];

static __device__ inline unsigned short f2bfu(float x) {
  unsigned u = __builtin_bit_cast(unsigned, x);
  u += 0x7fffu + ((u >> 16) & 1u);   // round-to-nearest-even
  return (unsigned short)(u >> 16);
}

// ---------------- D matrix: 256 blocks x 256 threads ----------------
// D[k][n] = sqrt(2/N) * cos(pi*(n+0.5)*k/N), row 0 scaled by 1/sqrt(2).
// Phase reduced exactly in integers: angle = pi*q/512, q = k*(2n+1) mod 1024.
__global__ void compute_D() {
  int k = blockIdx.x;
  int n = threadIdx.x;
  int q = (k * (2 * n + 1)) & 1023;
  float c = cosf((float)q * (float)(M_PI / 512.0));
  float v = 0.08838834764831845f * c;              // sqrt(2/256)
  if (k == 0) v *= 0.70710678118654752f;
  g_D[k][n] = v;
}

// ---------------- H = D diag(m) D : 32*32 blocks x 256 threads ----------------
// Block = (step s, 8-row group i0). a[r][k] = D[i0+r][k]*m_k staged in LDS (broadcast reads).
// H[i][j] = sum_k a[i-i0][k] * D[k][j]  (D[k][j] coalesced, L2-resident).
__global__ void compute_H(const float* __restrict__ sigmas) {
  __shared__ float a[8][NN];
  int s = blockIdx.x >> 5;
  int i0 = (blockIdx.x & 31) * 8;
  int j = threadIdx.x;

  float sg = sigmas[s];
  float t = 0.5f * sg * sg;
  float fk = (float)M_PI * (float)j * (1.0f / (float)NN);
  float m = expf(-fk * fk * t);
#pragma unroll
  for (int r = 0; r < 8; ++r) a[r][j] = g_D[i0 + r][j] * m;
  __syncthreads();

  float acc[8];
#pragma unroll
  for (int r = 0; r < 8; ++r) acc[r] = 0.f;
  for (int k = 0; k < NN; ++k) {
    float d = g_D[k][j];
#pragma unroll
    for (int r = 0; r < 8; ++r) acc[r] += a[r][k] * d;
  }
#pragma unroll
  for (int r = 0; r < 8; ++r) g_H[s][i0 + r][j] = f2bfu(acc[r]);
}

// ---------------- main fused kernel ----------------
// grid 768 = (img 0..383) * 2 halves; block 512 threads = 8 waves.
// Phase 1: Z[k][j] = sum_m X[k][m] * H[j0+j][m]   (Z = X H^T), Z^T -> LDS (bf16, swizzled)
// Phase 2: out[i][j0+j] = sum_k H[i][k] * Z[k][j]
__global__ __launch_bounds__(512, 2) void dct_blur_main(
    const float* __restrict__ x, const int* __restrict__ steps,
    float* __restrict__ out) {
  __shared__ __align__(16) unsigned short Zt[128 * 256];  // [j][k] swizzled

  int bid = blockIdx.x;
  int img = bid >> 1;
  int half = bid & 1;
  int b = img / 3;
  int s = steps[b];

  const float* X = x + (size_t)img * (NN * NN);
  float* O = out + (size_t)img * (NN * NN);
  const unsigned short* H = &g_H[s][0][0];

  int tid = (int)threadIdx.x;
  int lane = tid & 63;
  int w = tid >> 6;     // 0..7
  int wr = w >> 1;      // 0..3 : 64-row band
  int wc = w & 1;       // 0..1 : 64-col band within the 128-col half
  int l16 = lane & 15;
  int hi = lane >> 4;   // 0..3

  int j0 = half * 128;
  int mrow0 = wr * 64;
  int ncol0 = wc * 64;

  // ================= Phase 1 =================
  f32x4 acc[4][4];
#pragma unroll
  for (int mi = 0; mi < 4; ++mi)
#pragma unroll
    for (int ni = 0; ni < 4; ++ni)
      acc[mi][ni] = (f32x4){0.f, 0.f, 0.f, 0.f};

#pragma unroll 2
  for (int kk = 0; kk < 8; ++kk) {
    int m0 = kk * 32;
    bf16x8 a[4], bb[4];
#pragma unroll
    for (int mi = 0; mi < 4; ++mi) {
      int row = mrow0 + mi * 16 + l16;              // X row (= Z k-index)
      const f32x4* p = reinterpret_cast<const f32x4*>(X + row * NN + m0 + hi * 8);
      f32x4 v0 = p[0], v1 = p[1];
      u16x8 r;
#pragma unroll
      for (int e = 0; e < 4; ++e) { r[e] = f2bfu(v0[e]); r[4 + e] = f2bfu(v1[e]); }
      a[mi] = __builtin_bit_cast(bf16x8, r);
    }
#pragma unroll
    for (int ni = 0; ni < 4; ++ni) {
      int hrow = j0 + ncol0 + ni * 16 + l16;        // H row (= output col j)
      u16x8 g = *reinterpret_cast<const u16x8*>(H + hrow * NN + m0 + hi * 8);
      bb[ni] = __builtin_bit_cast(bf16x8, g);
    }
#pragma unroll
    for (int mi = 0; mi < 4; ++mi)
#pragma unroll
      for (int ni = 0; ni < 4; ++ni)
        acc[mi][ni] = __builtin_amdgcn_mfma_f32_16x16x32_bf16(a[mi], bb[ni], acc[mi][ni], 0, 0, 0);
  }

  // write Z^T to LDS: element (j, k) at ushort idx ((j<<8)+k) ^ ((j&7)<<3)
#pragma unroll
  for (int mi = 0; mi < 4; ++mi) {
#pragma unroll
    for (int ni = 0; ni < 4; ++ni) {
      int j = ncol0 + ni * 16 + l16;
      int kb = mrow0 + mi * 16 + 4 * hi;
      u16x4 pk;
#pragma unroll
      for (int r = 0; r < 4; ++r) pk[r] = f2bfu(acc[mi][ni][r]);
      int idx = ((j << 8) + kb) ^ ((j & 7) << 3);
      *reinterpret_cast<u16x4*>(&Zt[idx]) = pk;
    }
  }

  __syncthreads();

  // ================= Phase 2 =================
  f32x4 acc2[4][4];
#pragma unroll
  for (int mi = 0; mi < 4; ++mi)
#pragma unroll
    for (int ni = 0; ni < 4; ++ni)
      acc2[mi][ni] = (f32x4){0.f, 0.f, 0.f, 0.f};

#pragma unroll 2
  for (int kk = 0; kk < 8; ++kk) {
    int k0 = kk * 32;
    bf16x8 a2[4], b2[4];
#pragma unroll
    for (int mi = 0; mi < 4; ++mi) {
      int irow = mrow0 + mi * 16 + l16;             // output row i
      u16x8 g = *reinterpret_cast<const u16x8*>(H + irow * NN + k0 + hi * 8);
      a2[mi] = __builtin_bit_cast(bf16x8, g);
    }
#pragma unroll
    for (int ni = 0; ni < 4; ++ni) {
      int jr = ncol0 + ni * 16 + l16;
      int idx = ((jr << 8) + k0 + hi * 8) ^ ((jr & 7) << 3);
      u16x8 z = *reinterpret_cast<const u16x8*>(&Zt[idx]);
      b2[ni] = __builtin_bit_cast(bf16x8, z);
    }
#pragma unroll
    for (int mi = 0; mi < 4; ++mi)
#pragma unroll
      for (int ni = 0; ni < 4; ++ni)
        acc2[mi][ni] = __builtin_amdgcn_mfma_f32_16x16x32_bf16(a2[mi], b2[ni], acc2[mi][ni], 0, 0, 0);
  }

  // epilogue: fp32 store
#pragma unroll
  for (int mi = 0; mi < 4; ++mi) {
#pragma unroll
    for (int ni = 0; ni < 4; ++ni) {
      int ibase = mrow0 + mi * 16 + 4 * hi;
      int jg = j0 + ncol0 + ni * 16 + l16;
#pragma unroll
      for (int r = 0; r < 4; ++r)
        O[(ibase + r) * NN + jg] = acc2[mi][ni][r];
    }
  }
}

extern "C" void kernel_launch(void* const* d_in, const int* in_sizes, int n_in,
                              void* d_out, int out_size, void* d_ws, size_t ws_size,
                              hipStream_t stream) {
  (void)in_sizes; (void)n_in; (void)out_size; (void)d_ws; (void)ws_size;
  const float* x = (const float*)d_in[0];
  const float* sigmas = (const float*)d_in[1];
  const int* steps = (const int*)d_in[2];
  float* out = (float*)d_out;

  compute_D<<<dim3(NN), dim3(NN), 0, stream>>>();
  compute_H<<<dim3(NSTEP * 32), dim3(NN), 0, stream>>>(sigmas);
  dct_blur_main<<<dim3(768), dim3(512), 0, stream>>>(x, steps, out);
}